// Round 7
// baseline (304.126 us; speedup 1.0000x reference)
//
#include <hip/hip_runtime.h>
#include <math.h>

// Problem constants (from reference): B=32, C=2, L=262144, K=4
#define B_N 32
#define C_N 2
#define L_N 262144
#define K_N 4
#define NSEQ (B_N * C_N)            // 64 independent sequences
#define CHUNK 32                    // samples per thread (in registers)
#define THREADS 256                 // threads per block
#define BLKSAMP (CHUNK * THREADS)   // 8192 samples per block
#define NBLK_SEQ (L_N / BLKSAMP)    // 32 blocks per sequence
#define NBLK_TOT (NSEQ * NBLK_SEQ)  // 2048 blocks
#define NLVL 8                      // log2(THREADS): KS levels / bit-decomp bits
#define ROWW 33                     // LDS window row stride (bank-conflict-free)
#define FLAG_READY 0x1F2E3D4Cu

// d_ws float layout (35456 floats = 141.8 KB — same footprint as proven R6):
//   [coef : 32*20   =   640]
//   [PL   : 32*8*64 = 16384]  A^(32*2^l) = A^(2^(5+l)), l=0..7, per b
//   [AGG  : 2048*8  = 16384]  block zero-state aggregates (atomic payload)
//   [FLAG : 2048    =  2048]  per-block ready flags (cleared by prep)
#define WS_COEF 0
#define WS_PL   (B_N * 20)
#define WS_AGG  (WS_PL + B_N * NLVL * 64)
#define WS_FLAG (WS_AGG + NBLK_TOT * 8)

// ---------------------------------------------------------------------------
// K1: per-batch coefficient prep + transition-matrix powers (fp64) + flag clear.
// 32 blocks x 64 threads; thread (b,t) also clears flag[b*64+t] (2048 total).
// ---------------------------------------------------------------------------
__global__ __launch_bounds__(64) void svf_prep(
    const float* __restrict__ twoR, const float* __restrict__ Graw,
    const float* __restrict__ c_hp, const float* __restrict__ c_bp,
    const float* __restrict__ c_lp, float* __restrict__ ws)
{
    const int b = blockIdx.x;
    const int t = threadIdx.x;

    // clear the ready flags for this launch (poison-proof protocol)
    ((unsigned*)(ws + WS_FLAG))[b * 64 + t] = 0u;

    __shared__ double cf[K_N][5];   // b0,b1,b2,a1,a2 (normalized, a0==1)
    __shared__ double M[8][8];

    if (t < K_N) {
        const int k = t;
        double g  = (double)Graw[b * K_N + k];
        double tr = (double)twoR[b * K_N + k];
        double hp = (double)c_hp[b * K_N + k];
        double bp = (double)c_bp[b * K_N + k];
        double lp = (double)c_lp[b * K_N + k];
        double sg = 1.0 / (1.0 + exp(-g));
        double G  = tan(1.5707963267948966 * sg);
        double R  = log1p(exp(tr)) * 1.4426950408889634 + 0.01; // softplus/ln2 + .01
        double G2 = G * G;
        double b0 = hp + bp * G + lp * G2;
        double b1 = -2.0 * hp + 2.0 * lp * G2;
        double b2 = hp - bp * G + lp * G2;
        double a0 = 1.0 + G2 + R * G;
        double a1 = 2.0 * G2 - 2.0;
        double a2 = 1.0 + G2 - R * G;
        cf[k][0] = b0 / a0; cf[k][1] = b1 / a0; cf[k][2] = b2 / a0;
        cf[k][3] = a1 / a0; cf[k][4] = a2 / a0;
    }
    __syncthreads();

    if (t < 20) ws[WS_COEF + b * 20 + t] = (float)cf[t / 5][t % 5];

    // Build A columns: one cascade step from s = e_t, x = 0.
    if (t < 8) {
        double s[8];
        #pragma unroll
        for (int i = 0; i < 8; ++i) s[i] = (i == t) ? 1.0 : 0.0;
        double in = 0.0;
        #pragma unroll
        for (int k = 0; k < K_N; ++k) {
            double y   = cf[k][0] * in + s[2 * k];
            double s1n = cf[k][1] * in - cf[k][3] * y + s[2 * k + 1];
            double s2n = cf[k][2] * in - cf[k][4] * y;
            s[2 * k] = s1n; s[2 * k + 1] = s2n; in = y;
        }
        #pragma unroll
        for (int i = 0; i < 8; ++i) M[i][t] = s[i];
    }
    __syncthreads();

    // Repeated squaring: after p squarings M = A^(2^p). Store A^(2^(5+l)), l=0..7.
    const int i = t >> 3, j = t & 7;
    for (int p = 1; p <= 12; ++p) {
        double acc = 0.0;
        #pragma unroll
        for (int k = 0; k < 8; ++k) acc += M[i][k] * M[k][j];
        __syncthreads();
        M[i][j] = acc;
        __syncthreads();
        if (p >= 5) ws[WS_PL + (b * NLVL + (p - 5)) * 64 + t] = (float)acc;
    }
}

// ---------------------------------------------------------------------------
// Fused 4-biquad cascade step (normalized coefficients). 20 VALU ops/sample.
// ---------------------------------------------------------------------------
__device__ __forceinline__ float cascade_step(const float cf[20], float s[8], float in)
{
    #pragma unroll
    for (int k = 0; k < K_N; ++k) {
        float y  = fmaf(cf[k * 5 + 0], in, s[2 * k]);
        float t1 = fmaf(cf[k * 5 + 1], in, s[2 * k + 1]);
        float n1 = fmaf(-cf[k * 5 + 3], y, t1);
        float n2 = fmaf(-cf[k * 5 + 4], y, cf[k * 5 + 2] * in);
        s[2 * k] = n1; s[2 * k + 1] = n2;
        in = y;
    }
    return in;
}

// ---------------------------------------------------------------------------
// Single fused kernel: load x once -> regs; zero-state cascade; intra-block
// KS scan; publish aggregate (device-scope, release flag); wave-0 waits on
// predecessor aggregates (ascending-ID dispatch invariant, rocPRIM-style),
// folds S_blk; per-thread bit-decomp correction; final cascade; store y once.
// ---------------------------------------------------------------------------
__global__ __launch_bounds__(THREADS, 4) void svf_fused(
    const float* __restrict__ x, float* __restrict__ ws, float* __restrict__ out)
{
    const int seq  = blockIdx.x >> 5;          // / NBLK_SEQ
    const int blk  = blockIdx.x & (NBLK_SEQ - 1);
    const int tid  = threadIdx.x;
    const int b    = seq >> 1;
    const int myw  = tid >> 6, lane = tid & 63;

    __shared__ float smem[THREADS * 9];        // staging window ∪ KS buffer tb
    __shared__ float Pm[NLVL * 64];            // A^(32*2^l)
    __shared__ float Pb[64];                   // A^8192 = Pm[7]^2
    __shared__ float fl[NBLK_SEQ][8];          // predecessor aggregates
    __shared__ float sbv[8];                   // folded block-initial state

    for (int q = tid; q < NLVL * 64; q += THREADS)
        Pm[q] = ws[WS_PL + b * NLVL * 64 + q];

    float cf[20];
    #pragma unroll
    for (int q = 0; q < 20; ++q) cf[q] = ws[WS_COEF + b * 20 + q];

    // ---- staged coalesced load: global -> LDS window -> registers ----
    const size_t base = (size_t)seq * L_N + (size_t)blk * BLKSAMP;
    const float4* xg4 = (const float4*)(x + base);
    float4 v4[8];
    #pragma unroll
    for (int j = 0; j < 8; ++j) v4[j] = xg4[tid + j * THREADS];
    float xr[CHUNK];
    #pragma unroll
    for (int r = 0; r < 4; ++r) {
        #pragma unroll
        for (int h = 0; h < 2; ++h) {
            const int fw = tid + h * THREADS;
            const int a  = (fw >> 3) * ROWW + (fw & 7) * 4;
            float4 v = v4[2 * r + h];
            smem[a] = v.x; smem[a + 1] = v.y; smem[a + 2] = v.z; smem[a + 3] = v.w;
        }
        __syncthreads();
        if (myw == r) {
            #pragma unroll
            for (int j = 0; j < CHUNK; ++j) xr[j] = smem[lane * ROWW + j];
        }
        __syncthreads();
    }

    // Pb = Pm[7]^2 (needs Pm valid: guaranteed by the staging barriers above)
    if (tid < 64) {
        const int r8 = tid >> 3, c8 = tid & 7;
        float acc = 0.0f;
        #pragma unroll
        for (int k = 0; k < 8; ++k)
            acc = fmaf(Pm[7 * 64 + r8 * 8 + k], Pm[7 * 64 + k * 8 + c8], acc);
        Pb[tid] = acc;
    }

    // ---- zero-state cascade ----
    float t[8] = {0, 0, 0, 0, 0, 0, 0, 0};
    #pragma unroll
    for (int j = 0; j < CHUNK; ++j) (void)cascade_step(cf, t, xr[j]);

    // ---- intra-block Kogge-Stone over 256 chunk maps (tb aliases window) ----
    for (int l = 0; l < NLVL; ++l) {
        const int d = 1 << l;
        #pragma unroll
        for (int q = 0; q < 8; ++q) smem[tid * 9 + q] = t[q];
        __syncthreads();
        float prev[8];
        const bool have = (tid >= d);
        if (have) {
            #pragma unroll
            for (int q = 0; q < 8; ++q) prev[q] = smem[(tid - d) * 9 + q];
        }
        __syncthreads();
        if (have) {
            #pragma unroll
            for (int r = 0; r < 8; ++r) {
                float acc = t[r];
                #pragma unroll
                for (int c = 0; c < 8; ++c)
                    acc = fmaf(Pm[l * 64 + r * 8 + c], prev[c], acc);
                t[r] = acc;
            }
        }
    }
    #pragma unroll
    for (int q = 0; q < 8; ++q) smem[tid * 9 + q] = t[q];   // publish inclusive
    __syncthreads();

    // ---- publish block aggregate (thread 255 holds the block total) ----
    float* aggp = ws + WS_AGG;
    unsigned* flagp = (unsigned*)(ws + WS_FLAG);
    if (tid == THREADS - 1) {
        #pragma unroll
        for (int q = 0; q < 8; ++q)
            __hip_atomic_store(&aggp[(size_t)blockIdx.x * 8 + q], t[q],
                               __ATOMIC_RELAXED, __HIP_MEMORY_SCOPE_AGENT);
        __threadfence();
        __hip_atomic_store(&flagp[blockIdx.x], FLAG_READY,
                           __ATOMIC_RELEASE, __HIP_MEMORY_SCOPE_AGENT);
    }

    // ---- wave 0: gather predecessor aggregates (parallel spin), fold S ----
    if (tid < 64) {
        if (lane < blk) {
            const int pj = (seq << 5) + lane;      // predecessor block id < blockIdx.x
            while (__hip_atomic_load(&flagp[pj], __ATOMIC_ACQUIRE,
                                     __HIP_MEMORY_SCOPE_AGENT) != FLAG_READY)
                __builtin_amdgcn_s_sleep(2);
            #pragma unroll
            for (int q = 0; q < 8; ++q)
                fl[lane][q] = __hip_atomic_load(&aggp[(size_t)pj * 8 + q],
                                                __ATOMIC_RELAXED, __HIP_MEMORY_SCOPE_AGENT);
        }
        if (lane < 8) {
            float tr_ = 0.0f;                      // row `lane` of running S
            for (int j = 0; j < blk; ++j) {
                float tc[8];
                #pragma unroll
                for (int c = 0; c < 8; ++c) tc[c] = __shfl(tr_, c);
                float acc = fl[j][lane];
                #pragma unroll
                for (int c = 0; c < 8; ++c) acc = fmaf(Pb[lane * 8 + c], tc[c], acc);
                tr_ = acc;
            }
            sbv[lane] = tr_;
        }
    }
    __syncthreads();

    // ---- per-thread correction: v = A^(32*tid) * S_blk (bit-decomp) ----
    float v[8];
    #pragma unroll
    for (int q = 0; q < 8; ++q) v[q] = sbv[q];
    #pragma unroll
    for (int l = 0; l < NLVL; ++l) {
        if ((tid >> l) & 1) {
            float nv[8];
            #pragma unroll
            for (int r = 0; r < 8; ++r) {
                float acc = 0.0f;
                #pragma unroll
                for (int c = 0; c < 8; ++c)
                    acc = fmaf(Pm[l * 64 + r * 8 + c], v[c], acc);
                nv[r] = acc;
            }
            #pragma unroll
            for (int q = 0; q < 8; ++q) v[q] = nv[q];
        }
    }

    // s0 = intra-block exclusive prefix (tb[tid-1]) + block correction
    float s[8];
    if (tid == 0) {
        #pragma unroll
        for (int q = 0; q < 8; ++q) s[q] = v[q];
    } else {
        #pragma unroll
        for (int q = 0; q < 8; ++q) s[q] = smem[(tid - 1) * 9 + q] + v[q];
    }
    __syncthreads();                              // tb dead; window reusable

    // ---- final cascade from registers ----
    #pragma unroll
    for (int j = 0; j < CHUNK; ++j) xr[j] = cascade_step(cf, s, xr[j]);

    // ---- staged coalesced store: registers -> LDS window -> global ----
    float4* og4 = (float4*)(out + base);
    for (int r = 0; r < 4; ++r) {
        if (myw == r) {
            #pragma unroll
            for (int j = 0; j < CHUNK; ++j) smem[lane * ROWW + j] = xr[j];
        }
        __syncthreads();
        #pragma unroll
        for (int h = 0; h < 2; ++h) {
            const int fw = tid + h * THREADS;
            const int a  = (fw >> 3) * ROWW + (fw & 7) * 4;
            og4[r * 512 + fw] =
                make_float4(smem[a], smem[a + 1], smem[a + 2], smem[a + 3]);
        }
        __syncthreads();
    }
}

// ---------------------------------------------------------------------------
extern "C" void kernel_launch(void* const* d_in, const int* in_sizes, int n_in,
                              void* d_out, int out_size, void* d_ws, size_t ws_size,
                              hipStream_t stream)
{
    (void)in_sizes; (void)n_in; (void)out_size; (void)ws_size;
    const float* x    = (const float*)d_in[0];
    const float* twoR = (const float*)d_in[1];
    const float* G    = (const float*)d_in[2];
    const float* chp  = (const float*)d_in[3];
    const float* cbp  = (const float*)d_in[4];
    const float* clp  = (const float*)d_in[5];
    float* out = (float*)d_out;
    float* ws  = (float*)d_ws;

    svf_prep <<<B_N, 64, 0, stream>>>(twoR, G, chp, cbp, clp, ws);
    svf_fused<<<NBLK_TOT, THREADS, 0, stream>>>(x, ws, out);
}

// Round 8
// 269.312 us; speedup vs baseline: 1.1293x; 1.1293x over previous
//
#include <hip/hip_runtime.h>
#include <math.h>

// Problem constants (from reference): B=32, C=2, L=262144, K=4
#define B_N 32
#define C_N 2
#define L_N 262144
#define K_N 4
#define NSEQ (B_N * C_N)            // 64 independent sequences
#define CHUNK 32                    // samples per thread (in registers)
#define THREADS 256                 // threads per block
#define BLKSAMP (CHUNK * THREADS)   // 8192 samples per block
#define NBLK_SEQ (L_N / BLKSAMP)    // 32 blocks per sequence
#define NBLK_TOT (NSEQ * NBLK_SEQ)  // 2048 blocks
#define NLVL 8                      // log2(THREADS): KS levels / bit-decomp bits
#define ROWW 33                     // LDS window row stride (bank-conflict-free)
#define FLAG_READY 0x1F2E3D4Cu

// d_ws float layout (35456 floats = 141.8 KB):
//   [coef : 32*20   =   640]
//   [PL   : 32*8*64 = 16384]  A^(32*2^l) = A^(2^(5+l)), l=0..7, per b
//   [AGG  : 2048*8  = 16384]  block zero-state aggregates (atomic payload)
//   [FLAG : 2048    =  2048]  per-block ready flags (cleared by prep)
#define WS_COEF 0
#define WS_PL   (B_N * 20)
#define WS_AGG  (WS_PL + B_N * NLVL * 64)
#define WS_FLAG (WS_AGG + NBLK_TOT * 8)

// ---------------------------------------------------------------------------
// K1: per-batch coefficient prep + transition-matrix powers (fp64) + flag clear.
// ---------------------------------------------------------------------------
__global__ __launch_bounds__(64) void svf_prep(
    const float* __restrict__ twoR, const float* __restrict__ Graw,
    const float* __restrict__ c_hp, const float* __restrict__ c_bp,
    const float* __restrict__ c_lp, float* __restrict__ ws)
{
    const int b = blockIdx.x;
    const int t = threadIdx.x;

    // clear the ready flags for this launch (poison-proof protocol)
    ((unsigned*)(ws + WS_FLAG))[b * 64 + t] = 0u;

    __shared__ double cf[K_N][5];   // b0,b1,b2,a1,a2 (normalized, a0==1)
    __shared__ double M[8][8];

    if (t < K_N) {
        const int k = t;
        double g  = (double)Graw[b * K_N + k];
        double tr = (double)twoR[b * K_N + k];
        double hp = (double)c_hp[b * K_N + k];
        double bp = (double)c_bp[b * K_N + k];
        double lp = (double)c_lp[b * K_N + k];
        double sg = 1.0 / (1.0 + exp(-g));
        double G  = tan(1.5707963267948966 * sg);
        double R  = log1p(exp(tr)) * 1.4426950408889634 + 0.01; // softplus/ln2 + .01
        double G2 = G * G;
        double b0 = hp + bp * G + lp * G2;
        double b1 = -2.0 * hp + 2.0 * lp * G2;
        double b2 = hp - bp * G + lp * G2;
        double a0 = 1.0 + G2 + R * G;
        double a1 = 2.0 * G2 - 2.0;
        double a2 = 1.0 + G2 - R * G;
        cf[k][0] = b0 / a0; cf[k][1] = b1 / a0; cf[k][2] = b2 / a0;
        cf[k][3] = a1 / a0; cf[k][4] = a2 / a0;
    }
    __syncthreads();

    if (t < 20) ws[WS_COEF + b * 20 + t] = (float)cf[t / 5][t % 5];

    // Build A columns: one cascade step from s = e_t, x = 0.
    if (t < 8) {
        double s[8];
        #pragma unroll
        for (int i = 0; i < 8; ++i) s[i] = (i == t) ? 1.0 : 0.0;
        double in = 0.0;
        #pragma unroll
        for (int k = 0; k < K_N; ++k) {
            double y   = cf[k][0] * in + s[2 * k];
            double s1n = cf[k][1] * in - cf[k][3] * y + s[2 * k + 1];
            double s2n = cf[k][2] * in - cf[k][4] * y;
            s[2 * k] = s1n; s[2 * k + 1] = s2n; in = y;
        }
        #pragma unroll
        for (int i = 0; i < 8; ++i) M[i][t] = s[i];
    }
    __syncthreads();

    // Repeated squaring: after p squarings M = A^(2^p). Store A^(2^(5+l)), l=0..7.
    const int i = t >> 3, j = t & 7;
    for (int p = 1; p <= 12; ++p) {
        double acc = 0.0;
        #pragma unroll
        for (int k = 0; k < 8; ++k) acc += M[i][k] * M[k][j];
        __syncthreads();
        M[i][j] = acc;
        __syncthreads();
        if (p >= 5) ws[WS_PL + (b * NLVL + (p - 5)) * 64 + t] = (float)acc;
    }
}

// ---------------------------------------------------------------------------
// Fused 4-biquad cascade step (normalized coefficients). 20 VALU ops/sample.
// ---------------------------------------------------------------------------
__device__ __forceinline__ float cascade_step(const float cf[20], float s[8], float in)
{
    #pragma unroll
    for (int k = 0; k < K_N; ++k) {
        float y  = fmaf(cf[k * 5 + 0], in, s[2 * k]);
        float t1 = fmaf(cf[k * 5 + 1], in, s[2 * k + 1]);
        float n1 = fmaf(-cf[k * 5 + 3], y, t1);
        float n2 = fmaf(-cf[k * 5 + 4], y, cf[k * 5 + 2] * in);
        s[2 * k] = n1; s[2 * k + 1] = n2;
        in = y;
    }
    return in;
}

// ---------------------------------------------------------------------------
// Single fused kernel. Identical to R7 except the predecessor wait:
// RELAXED polling (no per-iteration acquire/cache-invalidate), one ACQUIRE
// load after FLAG_READY observed, longer s_sleep backoff.
// ---------------------------------------------------------------------------
__global__ __launch_bounds__(THREADS, 4) void svf_fused(
    const float* __restrict__ x, float* __restrict__ ws, float* __restrict__ out)
{
    const int seq  = blockIdx.x >> 5;          // / NBLK_SEQ
    const int blk  = blockIdx.x & (NBLK_SEQ - 1);
    const int tid  = threadIdx.x;
    const int b    = seq >> 1;
    const int myw  = tid >> 6, lane = tid & 63;

    __shared__ float smem[THREADS * 9];        // staging window ∪ KS buffer tb
    __shared__ float Pm[NLVL * 64];            // A^(32*2^l)
    __shared__ float Pb[64];                   // A^8192 = Pm[7]^2
    __shared__ float fl[NBLK_SEQ][8];          // predecessor aggregates
    __shared__ float sbv[8];                   // folded block-initial state

    for (int q = tid; q < NLVL * 64; q += THREADS)
        Pm[q] = ws[WS_PL + b * NLVL * 64 + q];

    float cf[20];
    #pragma unroll
    for (int q = 0; q < 20; ++q) cf[q] = ws[WS_COEF + b * 20 + q];

    // ---- staged coalesced load: global -> LDS window -> registers ----
    const size_t base = (size_t)seq * L_N + (size_t)blk * BLKSAMP;
    const float4* xg4 = (const float4*)(x + base);
    float4 v4[8];
    #pragma unroll
    for (int j = 0; j < 8; ++j) v4[j] = xg4[tid + j * THREADS];
    float xr[CHUNK];
    #pragma unroll
    for (int r = 0; r < 4; ++r) {
        #pragma unroll
        for (int h = 0; h < 2; ++h) {
            const int fw = tid + h * THREADS;
            const int a  = (fw >> 3) * ROWW + (fw & 7) * 4;
            float4 v = v4[2 * r + h];
            smem[a] = v.x; smem[a + 1] = v.y; smem[a + 2] = v.z; smem[a + 3] = v.w;
        }
        __syncthreads();
        if (myw == r) {
            #pragma unroll
            for (int j = 0; j < CHUNK; ++j) xr[j] = smem[lane * ROWW + j];
        }
        __syncthreads();
    }

    // Pb = Pm[7]^2 (Pm valid: guaranteed by the staging barriers above)
    if (tid < 64) {
        const int r8 = tid >> 3, c8 = tid & 7;
        float acc = 0.0f;
        #pragma unroll
        for (int k = 0; k < 8; ++k)
            acc = fmaf(Pm[7 * 64 + r8 * 8 + k], Pm[7 * 64 + k * 8 + c8], acc);
        Pb[tid] = acc;
    }

    // ---- zero-state cascade ----
    float t[8] = {0, 0, 0, 0, 0, 0, 0, 0};
    #pragma unroll
    for (int j = 0; j < CHUNK; ++j) (void)cascade_step(cf, t, xr[j]);

    // ---- intra-block Kogge-Stone over 256 chunk maps (tb aliases window) ----
    for (int l = 0; l < NLVL; ++l) {
        const int d = 1 << l;
        #pragma unroll
        for (int q = 0; q < 8; ++q) smem[tid * 9 + q] = t[q];
        __syncthreads();
        float prev[8];
        const bool have = (tid >= d);
        if (have) {
            #pragma unroll
            for (int q = 0; q < 8; ++q) prev[q] = smem[(tid - d) * 9 + q];
        }
        __syncthreads();
        if (have) {
            #pragma unroll
            for (int r = 0; r < 8; ++r) {
                float acc = t[r];
                #pragma unroll
                for (int c = 0; c < 8; ++c)
                    acc = fmaf(Pm[l * 64 + r * 8 + c], prev[c], acc);
                t[r] = acc;
            }
        }
    }
    #pragma unroll
    for (int q = 0; q < 8; ++q) smem[tid * 9 + q] = t[q];   // publish inclusive
    __syncthreads();

    // ---- publish block aggregate (thread 255 holds the block total) ----
    float* aggp = ws + WS_AGG;
    unsigned* flagp = (unsigned*)(ws + WS_FLAG);
    if (tid == THREADS - 1) {
        #pragma unroll
        for (int q = 0; q < 8; ++q)
            __hip_atomic_store(&aggp[(size_t)blockIdx.x * 8 + q], t[q],
                               __ATOMIC_RELAXED, __HIP_MEMORY_SCOPE_AGENT);
        __threadfence();
        __hip_atomic_store(&flagp[blockIdx.x], FLAG_READY,
                           __ATOMIC_RELEASE, __HIP_MEMORY_SCOPE_AGENT);
    }

    // ---- wave 0: gather predecessor aggregates, fold S_blk ----
    // Poll RELAXED (no cache-invalidating acquire in the loop); one ACQUIRE
    // after observation orders the payload reads.
    if (tid < 64) {
        if (lane < blk) {
            const int pj = (seq << 5) + lane;      // predecessor id < blockIdx.x
            while (__hip_atomic_load(&flagp[pj], __ATOMIC_RELAXED,
                                     __HIP_MEMORY_SCOPE_AGENT) != FLAG_READY)
                __builtin_amdgcn_s_sleep(8);
            (void)__hip_atomic_load(&flagp[pj], __ATOMIC_ACQUIRE,
                                    __HIP_MEMORY_SCOPE_AGENT);
            #pragma unroll
            for (int q = 0; q < 8; ++q)
                fl[lane][q] = __hip_atomic_load(&aggp[(size_t)pj * 8 + q],
                                                __ATOMIC_RELAXED, __HIP_MEMORY_SCOPE_AGENT);
        }
        if (lane < 8) {
            float tr_ = 0.0f;                      // row `lane` of running S
            for (int j = 0; j < blk; ++j) {
                float tc[8];
                #pragma unroll
                for (int c = 0; c < 8; ++c) tc[c] = __shfl(tr_, c);
                float acc = fl[j][lane];
                #pragma unroll
                for (int c = 0; c < 8; ++c) acc = fmaf(Pb[lane * 8 + c], tc[c], acc);
                tr_ = acc;
            }
            sbv[lane] = tr_;
        }
    }
    __syncthreads();

    // ---- per-thread correction: v = A^(32*tid) * S_blk (bit-decomp) ----
    float v[8];
    #pragma unroll
    for (int q = 0; q < 8; ++q) v[q] = sbv[q];
    #pragma unroll
    for (int l = 0; l < NLVL; ++l) {
        if ((tid >> l) & 1) {
            float nv[8];
            #pragma unroll
            for (int r = 0; r < 8; ++r) {
                float acc = 0.0f;
                #pragma unroll
                for (int c = 0; c < 8; ++c)
                    acc = fmaf(Pm[l * 64 + r * 8 + c], v[c], acc);
                nv[r] = acc;
            }
            #pragma unroll
            for (int q = 0; q < 8; ++q) v[q] = nv[q];
        }
    }

    // s0 = intra-block exclusive prefix (tb[tid-1]) + block correction
    float s[8];
    if (tid == 0) {
        #pragma unroll
        for (int q = 0; q < 8; ++q) s[q] = v[q];
    } else {
        #pragma unroll
        for (int q = 0; q < 8; ++q) s[q] = smem[(tid - 1) * 9 + q] + v[q];
    }
    __syncthreads();                              // tb dead; window reusable

    // ---- final cascade from registers ----
    #pragma unroll
    for (int j = 0; j < CHUNK; ++j) xr[j] = cascade_step(cf, s, xr[j]);

    // ---- staged coalesced store: registers -> LDS window -> global ----
    float4* og4 = (float4*)(out + base);
    for (int r = 0; r < 4; ++r) {
        if (myw == r) {
            #pragma unroll
            for (int j = 0; j < CHUNK; ++j) smem[lane * ROWW + j] = xr[j];
        }
        __syncthreads();
        #pragma unroll
        for (int h = 0; h < 2; ++h) {
            const int fw = tid + h * THREADS;
            const int a  = (fw >> 3) * ROWW + (fw & 7) * 4;
            og4[r * 512 + fw] =
                make_float4(smem[a], smem[a + 1], smem[a + 2], smem[a + 3]);
        }
        __syncthreads();
    }
}

// ---------------------------------------------------------------------------
extern "C" void kernel_launch(void* const* d_in, const int* in_sizes, int n_in,
                              void* d_out, int out_size, void* d_ws, size_t ws_size,
                              hipStream_t stream)
{
    (void)in_sizes; (void)n_in; (void)out_size; (void)ws_size;
    const float* x    = (const float*)d_in[0];
    const float* twoR = (const float*)d_in[1];
    const float* G    = (const float*)d_in[2];
    const float* chp  = (const float*)d_in[3];
    const float* cbp  = (const float*)d_in[4];
    const float* clp  = (const float*)d_in[5];
    float* out = (float*)d_out;
    float* ws  = (float*)d_ws;

    svf_prep <<<B_N, 64, 0, stream>>>(twoR, G, chp, cbp, clp, ws);
    svf_fused<<<NBLK_TOT, THREADS, 0, stream>>>(x, ws, out);
}